// Round 6
// baseline (328.630 us; speedup 1.0000x reference)
//
#include <hip/hip_runtime.h>
#include <math.h>

// Sparsemax over rows: out = max(z - tau, 0), tau s.t. sum(max(z-tau,0)) = 1.
//
// Round 6: structural software pipeline for the streaming phase.
//  - 4 rows per block (grid 2048). Row r+1's 16 KB of loads are issued before
//    row r's solve; first use is one full row-phase later, so the compiler's
//    exact waitcnt leaves them in flight during the solve. One vm-wait per row
//    (8 KB granularity) instead of 4 serialized 2 KB round trips.
//  - Raw `s_waitcnt lgkmcnt(0); s_barrier` (NO vmcnt drain) instead of
//    __syncthreads: __syncthreads lowers with vmcnt(0), which would drain the
//    prefetch at every block sync and kill the pipeline.
//  - 2 barriers per row: wave-local compaction (superset z > wmax_w-1, valid
//    since wmax_w <= zmax) + per-wave wmax to LDS; after barrier 1 every
//    thread derives zmax, filters, and runs the closed-form tau solve
//    (tau = max over valid candidates of (s_i-1)/n_i, n_i=#{c_j>=c_i},
//    s_i=sum{c_j>=c_i}, valid iff 1+n_i*c_i>s_i). Double-buffered LDS by row
//    parity makes 2 barriers/row race-free (each buffer's readers are >=2
//    barriers before its next writer).

constexpr int S   = 4096;
constexpr int TPB = 256;
constexpr int VPT = S / TPB;   // 16 values per thread
constexpr int NW  = TPB / 64;  // 4 waves per block
constexpr int RPB = 4;         // rows per block -> grid 2048 at B=8192
constexpr int CAP = 2048;      // per-buffer candidate capacity

#define NEGBIG (-1e30f)

__device__ __forceinline__ void bar_lgkm() {
    // block barrier draining LDS ops only -- global loads stay in flight
    asm volatile("s_waitcnt lgkmcnt(0)\n\ts_barrier" ::: "memory");
}

__global__ __launch_bounds__(TPB) void sparsemax_kernel(
    const float* __restrict__ scores,
    const int*   __restrict__ mask,
    float*       __restrict__ out,
    const int B)
{
    const int tid  = threadIdx.x;
    const int lane = tid & 63;
    const int wid  = tid >> 6;
    const int r0   = blockIdx.x * RPB;

    __shared__ float cand[2][CAP];
    __shared__ float wmaxs[2][NW];
    __shared__ float redT[2][NW];
    __shared__ float red[NW];      // fallback only
    __shared__ float red2[NW];     // fallback only
    __shared__ int   cnt[2];

    if (tid == 0) { cnt[0] = 0; cnt[1] = 0; }
    bar_lgkm();

    // ---- prologue: issue loads for row r0 ----
    float4 sv[VPT / 4];
    int4   mv[VPT / 4];
    {
        const float* srow = scores + (size_t)r0 * S;
        const int*   mrow = mask   + (size_t)r0 * S;
        #pragma unroll
        for (int ch = 0; ch < VPT / 4; ++ch) {
            const int idx = ch * (TPB * 4) + tid * 4;
            sv[ch] = *reinterpret_cast<const float4*>(srow + idx);
            mv[ch] = *reinterpret_cast<const int4*>(mrow + idx);
        }
    }

    for (int rr = 0; rr < RPB; ++rr) {
        const int row = r0 + rr;
        if (row >= B) break;
        const int b = rr & 1;

        // ---- consume prefetch (the single vm-wait of this row) ----
        float z[VPT];
        #pragma unroll
        for (int ch = 0; ch < VPT / 4; ++ch) {
            z[ch * 4 + 0] = mv[ch].x ? sv[ch].x : NEGBIG;
            z[ch * 4 + 1] = mv[ch].y ? sv[ch].y : NEGBIG;
            z[ch * 4 + 2] = mv[ch].z ? sv[ch].z : NEGBIG;
            z[ch * 4 + 3] = mv[ch].w ? sv[ch].w : NEGBIG;
        }

        // ---- issue prefetch for row r+1 (stays in flight across barriers) ----
        if (rr + 1 < RPB && row + 1 < B) {
            const float* srow = scores + (size_t)(row + 1) * S;
            const int*   mrow = mask   + (size_t)(row + 1) * S;
            #pragma unroll
            for (int ch = 0; ch < VPT / 4; ++ch) {
                const int idx = ch * (TPB * 4) + tid * 4;
                sv[ch] = *reinterpret_cast<const float4*>(srow + idx);
                mv[ch] = *reinterpret_cast<const int4*>(mrow + idx);
            }
        }

        // ---- wave-local max ----
        float wm = z[0];
        #pragma unroll
        for (int j = 1; j < VPT; ++j) wm = fmaxf(wm, z[j]);
        #pragma unroll
        for (int o = 1; o < 64; o <<= 1) wm = fmaxf(wm, __shfl_xor(wm, o, 64));

        // ---- compact wave-local candidate superset (z > wm-1) ----
        // wm <= zmax, so this is a superset of the true set {z > zmax-1}.
        // All-masked wave: wm = -1e30, wm-1 rounds to -1e30, nothing compacts.
        const float wthr = wm - 1.0f;
        #pragma unroll
        for (int j = 0; j < VPT; ++j) {
            if (z[j] > wthr) {
                const int p = atomicAdd(&cnt[b], 1);
                if (p < CAP) cand[b][p] = z[j];
            }
        }
        if (lane == 0) wmaxs[b][wid] = wm;

        bar_lgkm();                                    // barrier 1

        const float zmax = fmaxf(fmaxf(wmaxs[b][0], wmaxs[b][1]),
                                 fmaxf(wmaxs[b][2], wmaxs[b][3]));
        const float thr  = zmax - 1.0f;
        const int   m    = cnt[b];
        // zero the other counter for row rr+1 (its last reader finished
        // before barrier 2 of row rr-1, two barriers ago)
        if (tid == 0) cnt[b ^ 1] = 0;

        float t = NEGBIG;
        if (m <= CAP) {
            // ---- closed-form tau over true candidates (ci > thr) ----
            for (int i = tid; i < m; i += TPB) {
                const float ci = cand[b][i];
                if (ci > thr) {
                    float n = 0.0f, s = 0.0f;
                    for (int j = 0; j < m; ++j) {      // LDS broadcast reads
                        const float cj = cand[b][j];
                        if (cj >= ci) { n += 1.0f; s += cj; }
                    }
                    if (1.0f + n * ci > s) t = fmaxf(t, (s - 1.0f) / n);
                }
            }
        } else {
            // ---- fallback: block bisection on z (uniform path, m uniform) ----
            float lo = thr, hi = zmax;
            #pragma unroll 1
            for (int it = 0; it < 24; ++it) {
                const float mid = 0.5f * (lo + hi);
                float f = 0.0f;
                #pragma unroll
                for (int j = 0; j < VPT; ++j) f += fmaxf(z[j] - mid, 0.0f);
                #pragma unroll
                for (int o = 1; o < 64; o <<= 1) f += __shfl_xor(f, o, 64);
                if (lane == 0) red[wid] = f;
                bar_lgkm();
                f = (red[0] + red[1]) + (red[2] + red[3]);
                bar_lgkm();                            // protect red[] reuse
                if (f > 1.0f) lo = mid; else hi = mid;
            }
            const float tc = 0.5f * (lo + hi);
            float s = 0.0f, k = 0.0f;
            #pragma unroll
            for (int j = 0; j < VPT; ++j)
                if (z[j] > tc) { s += z[j]; k += 1.0f; }
            #pragma unroll
            for (int o = 1; o < 64; o <<= 1) {
                s += __shfl_xor(s, o, 64);
                k += __shfl_xor(k, o, 64);
            }
            if (lane == 0) { red[wid] = s; red2[wid] = k; }
            bar_lgkm();
            s = (red[0] + red[1]) + (red[2] + red[3]);
            k = (red2[0] + red2[1]) + (red2[2] + red2[3]);
            bar_lgkm();
            if (k < 0.5f) { k = 1.0f; s = zmax; }      // unreachable guard
            t = (s - 1.0f) / k;
        }

        // ---- block max of per-thread t -> tau ----
        #pragma unroll
        for (int o = 1; o < 64; o <<= 1) t = fmaxf(t, __shfl_xor(t, o, 64));
        if (lane == 0) redT[b][wid] = t;

        bar_lgkm();                                    // barrier 2

        const float tau = fmaxf(fmaxf(redT[b][0], redT[b][1]),
                                fmaxf(redT[b][2], redT[b][3]));

        // ---- write out (overlaps next row's compact phase) ----
        float* orow = out + (size_t)row * S;
        #pragma unroll
        for (int ch = 0; ch < VPT / 4; ++ch) {
            const int idx = ch * (TPB * 4) + tid * 4;
            float4 o4;
            o4.x = fmaxf(z[ch * 4 + 0] - tau, 0.0f);
            o4.y = fmaxf(z[ch * 4 + 1] - tau, 0.0f);
            o4.z = fmaxf(z[ch * 4 + 2] - tau, 0.0f);
            o4.w = fmaxf(z[ch * 4 + 3] - tau, 0.0f);
            *reinterpret_cast<float4*>(orow + idx) = o4;
        }
    }
}

extern "C" void kernel_launch(void* const* d_in, const int* in_sizes, int n_in,
                              void* d_out, int out_size, void* d_ws, size_t ws_size,
                              hipStream_t stream) {
    const float* scores = (const float*)d_in[0];
    const int*   mask   = (const int*)d_in[1];
    float*       out    = (float*)d_out;
    const int B = in_sizes[0] / S;  // 8192
    const int nblk = (B + RPB - 1) / RPB;
    sparsemax_kernel<<<dim3(nblk), dim3(TPB), 0, stream>>>(scores, mask, out, B);
}

// Round 8
// 323.352 us; speedup vs baseline: 1.0163x; 1.0163x over previous
//
#include <hip/hip_runtime.h>
#include <math.h>

// Sparsemax over rows: out = max(z - tau, 0), tau s.t. sum(max(z-tau,0)) = 1.
//
// Round 8 = round 7 structure with the addressing bug fixed (chunk stride is
// 256 floats = 64 lanes x 4 floats, NOT 1024 -- the 1024 caused out-of-bounds
// reads ~4 rows past the buffer end -> GPU memory fault).
//
// ONE WAVE PER ROW. 64 elems/lane in registers (z[64], fully unrolled), all
// reductions are 6-step __shfl_xor. No __syncthreads, no LDS, no atomics --
// waves are fully independent: no barrier convoying, no vmcnt(0) drains
// between phases; the CU overlaps one wave's bisection VALU with other waves'
// loads (m114 co-scheduling). Precedent: RMSNorm (same load->reduce->scale
// shape, one wave per row, no barriers) hits 4.89 TB/s vs our barrier-coupled
// 2.4 TB/s.
//
// Solve: 12-step bisection on [zmax-1, zmax] (root bracket since f(zmax-1)>=1)
// + exact refinement tau = (sum_{z>tc} z - 1)/#{z>tc}. Same math as the
// accepted baseline (absmax 9.8e-4).
//
// __launch_bounds__(256,4): 4 waves/EU -> VGPR cap 128 (z[64]+temps ~ 90).

constexpr int S   = 4096;
constexpr int TPB = 256;
constexpr int WPB = TPB / 64;   // 4 independent waves (rows) per block
constexpr int LPT = S / 64;     // 64 elements per lane
constexpr int NCH = LPT / 4;    // 16 float4/int4 chunk pairs

#define NEGBIG (-1e30f)

__global__ __launch_bounds__(TPB, 4) void sparsemax_kernel(
    const float* __restrict__ scores,
    const int*   __restrict__ mask,
    float*       __restrict__ out,
    const int B)
{
    const int lane = threadIdx.x & 63;
    const int row  = blockIdx.x * WPB + (threadIdx.x >> 6);
    if (row >= B) return;

    const float* srow = scores + (size_t)row * S;
    const int*   mrow = mask   + (size_t)row * S;
    float*       orow = out    + (size_t)row * S;

    // ---- load row: 16 chunks, each 64 lanes x 16 B = 256 floats ----
    float z[LPT];
    #pragma unroll
    for (int ch = 0; ch < NCH; ++ch) {
        const int idx = ch * 256 + lane * 4;
        const float4 s4 = *reinterpret_cast<const float4*>(srow + idx);
        const int4   m4 = *reinterpret_cast<const int4*>(mrow + idx);
        z[ch * 4 + 0] = m4.x ? s4.x : NEGBIG;
        z[ch * 4 + 1] = m4.y ? s4.y : NEGBIG;
        z[ch * 4 + 2] = m4.z ? s4.z : NEGBIG;
        z[ch * 4 + 3] = m4.w ? s4.w : NEGBIG;
    }

    // ---- row max (4-way ILP tree + wave shuffle reduce) ----
    float m0 = z[0], m1 = z[1], m2 = z[2], m3 = z[3];
    #pragma unroll
    for (int j = 4; j < LPT; j += 4) {
        m0 = fmaxf(m0, z[j + 0]);
        m1 = fmaxf(m1, z[j + 1]);
        m2 = fmaxf(m2, z[j + 2]);
        m3 = fmaxf(m3, z[j + 3]);
    }
    float mx = fmaxf(fmaxf(m0, m1), fmaxf(m2, m3));
    #pragma unroll
    for (int o = 1; o < 64; o <<= 1) mx = fmaxf(mx, __shfl_xor(mx, o, 64));

    // ---- bisection on f(tau) = sum(max(z-tau,0)) - 1, root in [mx-1, mx] ----
    float lo = mx - 1.0f, hi = mx;
    #pragma unroll 1
    for (int it = 0; it < 12; ++it) {
        const float mid = 0.5f * (lo + hi);
        float f0 = 0.f, f1 = 0.f, f2 = 0.f, f3 = 0.f;
        #pragma unroll
        for (int j = 0; j < LPT; j += 4) {
            f0 += fmaxf(z[j + 0] - mid, 0.f);
            f1 += fmaxf(z[j + 1] - mid, 0.f);
            f2 += fmaxf(z[j + 2] - mid, 0.f);
            f3 += fmaxf(z[j + 3] - mid, 0.f);
        }
        float f = (f0 + f1) + (f2 + f3);
        #pragma unroll
        for (int o = 1; o < 64; o <<= 1) f += __shfl_xor(f, o, 64);
        if (f > 1.0f) lo = mid; else hi = mid;
    }

    // ---- exact refinement: tau = (sum_{z > tc} z - 1) / count ----
    const float tc = 0.5f * (lo + hi);
    float s0 = 0.f, s1 = 0.f, k0 = 0.f, k1 = 0.f;
    #pragma unroll
    for (int j = 0; j < LPT; j += 2) {
        if (z[j + 0] > tc) { s0 += z[j + 0]; k0 += 1.f; }
        if (z[j + 1] > tc) { s1 += z[j + 1]; k1 += 1.f; }
    }
    float s = s0 + s1, k = k0 + k1;
    #pragma unroll
    for (int o = 1; o < 64; o <<= 1) {
        s += __shfl_xor(s, o, 64);
        k += __shfl_xor(k, o, 64);
    }
    if (k < 0.5f) { k = 1.0f; s = mx; }   // unreachable guard (>=1 valid/row)
    const float tau = (s - 1.0f) / k;

    // ---- write out ----
    #pragma unroll
    for (int ch = 0; ch < NCH; ++ch) {
        const int idx = ch * 256 + lane * 4;
        float4 o4;
        o4.x = fmaxf(z[ch * 4 + 0] - tau, 0.0f);
        o4.y = fmaxf(z[ch * 4 + 1] - tau, 0.0f);
        o4.z = fmaxf(z[ch * 4 + 2] - tau, 0.0f);
        o4.w = fmaxf(z[ch * 4 + 3] - tau, 0.0f);
        *reinterpret_cast<float4*>(orow + idx) = o4;
    }
}

extern "C" void kernel_launch(void* const* d_in, const int* in_sizes, int n_in,
                              void* d_out, int out_size, void* d_ws, size_t ws_size,
                              hipStream_t stream) {
    const float* scores = (const float*)d_in[0];
    const int*   mask   = (const int*)d_in[1];
    float*       out    = (float*)d_out;
    const int B = in_sizes[0] / S;  // 8192
    const int nblk = (B + WPB - 1) / WPB;   // 2048
    sparsemax_kernel<<<dim3(nblk), dim3(TPB), 0, stream>>>(scores, mask, out, B);
}

// Round 9
// 315.804 us; speedup vs baseline: 1.0406x; 1.0239x over previous
//
#include <hip/hip_runtime.h>
#include <math.h>

// Sparsemax over rows: out = max(z - tau, 0), tau s.t. sum(max(z-tau,0)) = 1.
//
// Round 9 = round 8 structure (ONE WAVE PER ROW, barrier-free) with the spill
// fixed. Round 8's counters showed the compiler snapped to the 64-VGPR
// occupancy step and spilled z[64] to scratch (WRITE_SIZE 131072->184320 KB,
// FETCH +26 MiB, occupancy 36%). amdgpu_waves_per_eu(4,4) pins exactly 4
// waves/EU: with max=4 there is no occupancy reward below 64 VGPRs, so the
// allocator keeps z[64] register-resident (~90-110 VGPRs, cap 128).
//
// Structure: 64 elems/lane in registers, all reductions 6-step __shfl_xor.
// No __syncthreads, no LDS, no atomics -- waves fully independent: no barrier
// convoying, no vmcnt(0) drains between phases; CU overlaps one wave's
// bisection VALU with other waves' loads (m114). Precedent: RMSNorm
// (one wave per row, no barriers) hits 4.89 TB/s vs our coupled 2.4 TB/s.
//
// Solve: 12-step bisection on [zmax-1, zmax] (root bracket since f(zmax-1)>=1)
// + exact refinement tau = (sum_{z>tc} z - 1)/#{z>tc}. Baseline math,
// absmax 9.8e-4.

constexpr int S   = 4096;
constexpr int TPB = 256;
constexpr int WPB = TPB / 64;   // 4 independent waves (rows) per block
constexpr int LPT = S / 64;     // 64 elements per lane
constexpr int NCH = LPT / 4;    // 16 float4/int4 chunk pairs

#define NEGBIG (-1e30f)

__global__ __launch_bounds__(TPB)
__attribute__((amdgpu_waves_per_eu(4, 4)))
void sparsemax_kernel(
    const float* __restrict__ scores,
    const int*   __restrict__ mask,
    float*       __restrict__ out,
    const int B)
{
    const int lane = threadIdx.x & 63;
    const int row  = blockIdx.x * WPB + (threadIdx.x >> 6);
    if (row >= B) return;

    const float* srow = scores + (size_t)row * S;
    const int*   mrow = mask   + (size_t)row * S;
    float*       orow = out    + (size_t)row * S;

    // ---- load row: 16 chunks, each 64 lanes x 16 B = 256 floats ----
    float z[LPT];
    #pragma unroll
    for (int ch = 0; ch < NCH; ++ch) {
        const int idx = ch * 256 + lane * 4;
        const float4 s4 = *reinterpret_cast<const float4*>(srow + idx);
        const int4   m4 = *reinterpret_cast<const int4*>(mrow + idx);
        z[ch * 4 + 0] = m4.x ? s4.x : NEGBIG;
        z[ch * 4 + 1] = m4.y ? s4.y : NEGBIG;
        z[ch * 4 + 2] = m4.z ? s4.z : NEGBIG;
        z[ch * 4 + 3] = m4.w ? s4.w : NEGBIG;
    }

    // ---- row max (4-way ILP tree + wave shuffle reduce) ----
    float m0 = z[0], m1 = z[1], m2 = z[2], m3 = z[3];
    #pragma unroll
    for (int j = 4; j < LPT; j += 4) {
        m0 = fmaxf(m0, z[j + 0]);
        m1 = fmaxf(m1, z[j + 1]);
        m2 = fmaxf(m2, z[j + 2]);
        m3 = fmaxf(m3, z[j + 3]);
    }
    float mx = fmaxf(fmaxf(m0, m1), fmaxf(m2, m3));
    #pragma unroll
    for (int o = 1; o < 64; o <<= 1) mx = fmaxf(mx, __shfl_xor(mx, o, 64));

    // ---- bisection on f(tau) = sum(max(z-tau,0)) - 1, root in [mx-1, mx] ----
    float lo = mx - 1.0f, hi = mx;
    #pragma unroll 1
    for (int it = 0; it < 12; ++it) {
        const float mid = 0.5f * (lo + hi);
        float f0 = 0.f, f1 = 0.f, f2 = 0.f, f3 = 0.f;
        #pragma unroll
        for (int j = 0; j < LPT; j += 4) {
            f0 += fmaxf(z[j + 0] - mid, 0.f);
            f1 += fmaxf(z[j + 1] - mid, 0.f);
            f2 += fmaxf(z[j + 2] - mid, 0.f);
            f3 += fmaxf(z[j + 3] - mid, 0.f);
        }
        float f = (f0 + f1) + (f2 + f3);
        #pragma unroll
        for (int o = 1; o < 64; o <<= 1) f += __shfl_xor(f, o, 64);
        if (f > 1.0f) lo = mid; else hi = mid;
    }

    // ---- exact refinement: tau = (sum_{z > tc} z - 1) / count ----
    const float tc = 0.5f * (lo + hi);
    float s0 = 0.f, s1 = 0.f, k0 = 0.f, k1 = 0.f;
    #pragma unroll
    for (int j = 0; j < LPT; j += 2) {
        if (z[j + 0] > tc) { s0 += z[j + 0]; k0 += 1.f; }
        if (z[j + 1] > tc) { s1 += z[j + 1]; k1 += 1.f; }
    }
    float s = s0 + s1, k = k0 + k1;
    #pragma unroll
    for (int o = 1; o < 64; o <<= 1) {
        s += __shfl_xor(s, o, 64);
        k += __shfl_xor(k, o, 64);
    }
    if (k < 0.5f) { k = 1.0f; s = mx; }   // unreachable guard (>=1 valid/row)
    const float tau = (s - 1.0f) / k;

    // ---- write out ----
    #pragma unroll
    for (int ch = 0; ch < NCH; ++ch) {
        const int idx = ch * 256 + lane * 4;
        float4 o4;
        o4.x = fmaxf(z[ch * 4 + 0] - tau, 0.0f);
        o4.y = fmaxf(z[ch * 4 + 1] - tau, 0.0f);
        o4.z = fmaxf(z[ch * 4 + 2] - tau, 0.0f);
        o4.w = fmaxf(z[ch * 4 + 3] - tau, 0.0f);
        *reinterpret_cast<float4*>(orow + idx) = o4;
    }
}

extern "C" void kernel_launch(void* const* d_in, const int* in_sizes, int n_in,
                              void* d_out, int out_size, void* d_ws, size_t ws_size,
                              hipStream_t stream) {
    const float* scores = (const float*)d_in[0];
    const int*   mask   = (const int*)d_in[1];
    float*       out    = (float*)d_out;
    const int B = in_sizes[0] / S;  // 8192
    const int nblk = (B + WPB - 1) / WPB;   // 2048
    sparsemax_kernel<<<dim3(nblk), dim3(TPB), 0, stream>>>(scores, mask, out, B);
}

// Round 10
// 315.543 us; speedup vs baseline: 1.0415x; 1.0008x over previous
//
#include <hip/hip_runtime.h>
#include <math.h>

// Sparsemax over rows: out = max(z - tau, 0), tau s.t. sum(max(z-tau,0)) = 1.
//
// Round 10: exploit OUTPUT SPARSITY. Sparsemax output is ~99.7% zeros
// (~13 nonzeros per 4096-row = the candidate set z > zmax-1 we already
// compact). Previously the kernel densely wrote 128 MiB of mostly zeros
// (and re-read 256 MiB from L2 to recompute z for that phase -- VGPR=20
// across rounds proves the compiler rematerializes z per phase). Now:
//   1. hipMemsetAsync zeroes the output (pure write stream at memset BW).
//   2. Kernel compacts (value, index) candidate pairs, solves tau in closed
//      form (round-2 structure, measured best), scatters only entries with
//      cval > tau. Kernel becomes a read-only streaming reduction + tiny
//      scatter (RMSNorm shape, 4.89 TB/s precedent), and its write stream
//      no longer evicts the exactly-L3-sized (256 MiB) input set.
//
// tau closed form over candidates (z > zmax-1 is a superset of the support,
// since f(zmax-1) >= 1 => tau >= zmax-1): with n_i = #{c_j >= c_i},
// s_i = sum{c_j >= c_i}: tau = max over valid i of (s_i-1)/n_i, valid iff
// 1 + n_i*c_i > s_i. ((cs_k-1)/k increasing over valid sorted positions;
// tie groups share validity, so '>=' counting is exact.)
//
// Fallback m > CAP (unreachable for this data): block bisection + DENSE row
// write (that row ignores the memset).

constexpr int S   = 4096;
constexpr int TPB = 256;
constexpr int VPT = S / TPB;   // 16 values per thread
constexpr int NW  = TPB / 64;  // 4 waves per block
constexpr int CAP = 1024;      // candidate capacity (fallback beyond)

#define NEGBIG (-1e30f)

__global__ __launch_bounds__(TPB) void sparsemax_kernel(
    const float* __restrict__ scores,
    const int*   __restrict__ mask,
    float*       __restrict__ out)
{
    const int row  = blockIdx.x;
    const int tid  = threadIdx.x;
    const int lane = tid & 63;
    const int wid  = tid >> 6;

    const float* srow = scores + (size_t)row * S;
    const int*   mrow = mask   + (size_t)row * S;

    float z[VPT];
    #pragma unroll
    for (int ch = 0; ch < VPT / 4; ++ch) {
        const int idx = ch * (TPB * 4) + tid * 4;
        const float4 s4 = *reinterpret_cast<const float4*>(srow + idx);
        const int4   m4 = *reinterpret_cast<const int4*>(mrow + idx);
        z[ch * 4 + 0] = m4.x ? s4.x : NEGBIG;
        z[ch * 4 + 1] = m4.y ? s4.y : NEGBIG;
        z[ch * 4 + 2] = m4.z ? s4.z : NEGBIG;
        z[ch * 4 + 3] = m4.w ? s4.w : NEGBIG;
    }

    __shared__ float red[NW];
    __shared__ float red2[NW];
    __shared__ float cval[CAP];
    __shared__ int   cidx[CAP];
    __shared__ int   cnt;
    if (tid == 0) cnt = 0;

    // ---- row max ----
    float mx = z[0];
    #pragma unroll
    for (int j = 1; j < VPT; ++j) mx = fmaxf(mx, z[j]);
    #pragma unroll
    for (int o = 1; o < 64; o <<= 1) mx = fmaxf(mx, __shfl_xor(mx, o, 64));
    if (lane == 0) red[wid] = mx;
    __syncthreads();                                   // A (also covers cnt=0)
    const float zmax = fmaxf(fmaxf(red[0], red[1]), fmaxf(red[2], red[3]));
    const float thr  = zmax - 1.0f;   // tau is in [thr, zmax]

    // ---- compact candidates (value, column index) into LDS ----
    #pragma unroll
    for (int ch = 0; ch < VPT / 4; ++ch) {
        const int base = ch * (TPB * 4) + tid * 4;
        #pragma unroll
        for (int j = 0; j < 4; ++j) {
            const float v = z[ch * 4 + j];
            if (v > thr) {
                const int p = atomicAdd(&cnt, 1);
                if (p < CAP) { cval[p] = v; cidx[p] = base + j; }
            }
        }
    }
    __syncthreads();                                   // B (also frees red[] zmax reads)
    const int m = cnt;   // >= 1 (zmax is always a candidate)

    if (m <= CAP) {
        // ---- closed-form tau over candidates ----
        float t = NEGBIG;
        for (int i = tid; i < m; i += TPB) {           // threads >= m skip
            const float ci = cval[i];
            float n = 0.0f, s = 0.0f;
            for (int j = 0; j < m; ++j) {              // same j all lanes: LDS broadcast
                const float cj = cval[j];
                if (cj >= ci) { n += 1.0f; s += cj; }
            }
            if (1.0f + n * ci > s) t = fmaxf(t, (s - 1.0f) / n);
        }
        #pragma unroll
        for (int o = 1; o < 64; o <<= 1) t = fmaxf(t, __shfl_xor(t, o, 64));
        if (lane == 0) red[wid] = t;
        __syncthreads();                               // C
        const float tau = fmaxf(fmaxf(red[0], red[1]), fmaxf(red[2], red[3]));

        // ---- sparse scatter: only positive entries (rest stay memset-zero) ----
        float* orow = out + (size_t)row * S;
        for (int i = tid; i < m; i += TPB) {
            const float v = cval[i] - tau;
            if (v > 0.0f) orow[cidx[i]] = v;
        }
    } else {
        // ---- fallback: block bisection + dense row write (m > CAP) ----
        float lo = thr, hi = zmax;
        #pragma unroll 1
        for (int it = 0; it < 24; ++it) {
            const float mid = 0.5f * (lo + hi);
            float f = 0.0f;
            #pragma unroll
            for (int j = 0; j < VPT; ++j) f += fmaxf(z[j] - mid, 0.0f);
            #pragma unroll
            for (int o = 1; o < 64; o <<= 1) f += __shfl_xor(f, o, 64);
            __syncthreads();
            if (lane == 0) red[wid] = f;
            __syncthreads();
            f = (red[0] + red[1]) + (red[2] + red[3]);
            if (f > 1.0f) lo = mid; else hi = mid;
        }
        const float tc = 0.5f * (lo + hi);
        float s = 0.0f, k = 0.0f;
        #pragma unroll
        for (int j = 0; j < VPT; ++j)
            if (z[j] > tc) { s += z[j]; k += 1.0f; }
        #pragma unroll
        for (int o = 1; o < 64; o <<= 1) {
            s += __shfl_xor(s, o, 64);
            k += __shfl_xor(k, o, 64);
        }
        __syncthreads();
        if (lane == 0) { red[wid] = s; red2[wid] = k; }
        __syncthreads();
        s = (red[0] + red[1]) + (red[2] + red[3]);
        k = (red2[0] + red2[1]) + (red2[2] + red2[3]);
        if (k < 0.5f) { k = 1.0f; s = zmax; }          // unreachable guard
        const float tau = (s - 1.0f) / k;

        float* orow = out + (size_t)row * S;
        #pragma unroll
        for (int ch = 0; ch < VPT / 4; ++ch) {
            const int idx = ch * (TPB * 4) + tid * 4;
            float4 o4;
            o4.x = fmaxf(z[ch * 4 + 0] - tau, 0.0f);
            o4.y = fmaxf(z[ch * 4 + 1] - tau, 0.0f);
            o4.z = fmaxf(z[ch * 4 + 2] - tau, 0.0f);
            o4.w = fmaxf(z[ch * 4 + 3] - tau, 0.0f);
            *reinterpret_cast<float4*>(orow + idx) = o4;
        }
    }
}

extern "C" void kernel_launch(void* const* d_in, const int* in_sizes, int n_in,
                              void* d_out, int out_size, void* d_ws, size_t ws_size,
                              hipStream_t stream) {
    const float* scores = (const float*)d_in[0];
    const int*   mask   = (const int*)d_in[1];
    float*       out    = (float*)d_out;
    const int B = in_sizes[0] / S;  // 8192 (in_sizes are element counts)
    // zero the output (pure write stream at memset BW; graph-capture-safe),
    // then scatter only the ~13 nonzeros per row from the kernel.
    hipMemsetAsync(d_out, 0, (size_t)in_sizes[0] * sizeof(float), stream);
    sparsemax_kernel<<<dim3(B), dim3(TPB), 0, stream>>>(scores, mask, out);
}